// Round 17
// baseline (86.517 us; speedup 1.0000x reference)
//
#include <hip/hip_runtime.h>
#include <hip/hip_fp16.h>

// Boids ODE segment-sum v13: v12 retuned.
//   WIN 256->512 (NB=196): u8 sbkt, 256-entry tables, half the reservations.
//   SEPB 8192->12288 @ 1024 thr: 63KB LDS -> still 2 blocks/CU, runs avg ~62.
//   lofs folded into gbase (gbase[b] = reserved - ex): 1 fewer LDS read/edge.
//   accum: 512-node window, SPLIT=16, payload (local9<<23)|src23.
// ws need ~40MB; harness poison fill shows ws ~268MB.

#define BA1 5e-06f
#define BA2 0.0005f
#define BA3 1e-08f

#define NT 256        // threads per block (pack/accum)
#define NTS 1024      // threads per scatter block
#define NWAVE 4       // NT/64
#define SEPB 12288    // edges per scatter block (avg run ~62)
#define WIN 512       // receiver nodes per bucket
#define WSH 9         // log2(WIN)
#define SPLIT 16      // accum blocks per bucket
#define NBMAX 256     // max buckets
#define CAP 49152u    // per-bucket region capacity (multiple of 4)
#define FPS 4194304.f // fixed-point scale 2^22

// ---------------- K1: pack records + init cursors ----------------
// rec16[i] = {pos.x, pos.y, bitcast(f16(vel.x)|f16(vel.y)<<16), field}
__global__ void __launch_bounds__(NT)
k_pack(const float* __restrict__ pos, const float* __restrict__ vel,
       const float* __restrict__ field,
       int N, int NB, int PBLK,
       float4* __restrict__ rec16, unsigned* __restrict__ cursor) {
    int bx = blockIdx.x, tid = threadIdx.x;
    if (bx == PBLK) {
        for (int b = tid; b < NB; b += NT) cursor[b] = (unsigned)b * CAP;
        return;
    }
    int i = bx * NT + tid;
    if (i >= N) return;
    float2 p = *reinterpret_cast<const float2*>(pos + 2 * i);
    float2 v = *reinterpret_cast<const float2*>(vel + 2 * i);
    unsigned short sx = __half_as_ushort(__float2half(v.x));
    unsigned short sy = __half_as_ushort(__float2half(v.y));
    unsigned pv = (unsigned)sx | ((unsigned)sy << 16);
    rec16[i] = make_float4(p.x, p.y, __uint_as_float(pv), field[i]);
}

// ---------------- K2: multisplit scatter (1024 threads, 12 edges/thread) ----
__global__ void __launch_bounds__(NTS)
k_scatter(const int* __restrict__ dst, const int* __restrict__ src,
          int E, int NB,
          unsigned* __restrict__ cursor,
          unsigned* __restrict__ pk) {
    __shared__ unsigned lh[NBMAX];       // counts -> inclusive scan
    __shared__ unsigned lcur[NBMAX];     // running cursors (absolute sbuf slots)
    __shared__ unsigned gbase[NBMAX];    // reserved global base MINUS local ex
    __shared__ unsigned sbuf[SEPB];      // locally sorted payloads
    __shared__ unsigned char sbkt[SEPB]; // bucket id per sorted slot (u8)
    int blk = blockIdx.x, tid = threadIdx.x;
    int s = blk * SEPB, e = min(E, s + SEPB);

    if (tid < NBMAX) lh[tid] = 0u;
    __syncthreads();

    // pass 1: local histogram
    int k = s + 4 * tid;
    for (; k + 3 < e; k += 4 * NTS) {
        int4 d = *reinterpret_cast<const int4*>(dst + k);
        atomicAdd(&lh[d.x >> WSH], 1u);
        atomicAdd(&lh[d.y >> WSH], 1u);
        atomicAdd(&lh[d.z >> WSH], 1u);
        atomicAdd(&lh[d.w >> WSH], 1u);
    }
    {
        int rem = (e - s) & 3;
        if (tid < rem) atomicAdd(&lh[dst[e - rem + tid] >> WSH], 1u);
    }
    __syncthreads();

    // inclusive Hillis-Steele scan over NBMAX (first 256 threads, 1 elem each)
    for (int o = 1; o < NBMAX; o <<= 1) {
        unsigned v0 = 0u;
        if (tid < NBMAX && tid >= o) v0 = lh[tid - o];
        __syncthreads();
        if (tid < NBMAX) lh[tid] += v0;
        __syncthreads();
    }
    // per-bucket: count from scan diffs, reserve global run, fold ex into gbase
    if (tid < NBMAX) {
        unsigned inc = lh[tid];
        unsigned ex = (tid > 0) ? lh[tid - 1] : 0u;
        unsigned c = inc - ex;
        lcur[tid] = ex;
        if (tid < NB && c > 0u) {
            unsigned g = atomicAdd(&cursor[tid], c);
            gbase[tid] = g - ex;        // write phase: idx = gbase[b] + t
        }
    }
    __syncthreads();

    // pass 2: place payloads into LDS grouped by bucket
    k = s + 4 * tid;
    for (; k + 3 < e; k += 4 * NTS) {
        int4 d = *reinterpret_cast<const int4*>(dst + k);
        int4 j = *reinterpret_cast<const int4*>(src + k);
        int b0 = d.x >> WSH; unsigned r0 = atomicAdd(&lcur[b0], 1u);
        sbuf[r0] = ((unsigned)(d.x & (WIN - 1)) << 23) | (unsigned)j.x; sbkt[r0] = (unsigned char)b0;
        int b1 = d.y >> WSH; unsigned r1 = atomicAdd(&lcur[b1], 1u);
        sbuf[r1] = ((unsigned)(d.y & (WIN - 1)) << 23) | (unsigned)j.y; sbkt[r1] = (unsigned char)b1;
        int b2 = d.z >> WSH; unsigned r2 = atomicAdd(&lcur[b2], 1u);
        sbuf[r2] = ((unsigned)(d.z & (WIN - 1)) << 23) | (unsigned)j.z; sbkt[r2] = (unsigned char)b2;
        int b3 = d.w >> WSH; unsigned r3 = atomicAdd(&lcur[b3], 1u);
        sbuf[r3] = ((unsigned)(d.w & (WIN - 1)) << 23) | (unsigned)j.w; sbkt[r3] = (unsigned char)b3;
    }
    {
        int rem = (e - s) & 3;
        if (tid < rem) {
            int kk = e - rem + tid;
            int d = dst[kk];
            int b = d >> WSH; unsigned r = atomicAdd(&lcur[b], 1u);
            sbuf[r] = ((unsigned)(d & (WIN - 1)) << 23) | (unsigned)src[kk]; sbkt[r] = (unsigned char)b;
        }
    }
    __syncthreads();

    // write phase: consecutive slots in a bucket -> consecutive global addrs
    int ne = e - s;
    for (int t = tid; t < ne; t += NTS) {
        unsigned b = sbkt[t];
        unsigned idx = gbase[b] + (unsigned)t;
        if (idx < (b + 1u) * CAP)      // safety clamp; never hit statistically
            pk[idx] = sbuf[t];
    }
}

// ---------------- K3: accumulate, ONE u64 integer LDS atomic per edge ----------
__global__ void __launch_bounds__(NT, 5)
k_accum(const float4* __restrict__ rec16,
        const float* __restrict__ p_table,
        const int* __restrict__ ptype,
        const unsigned* __restrict__ pk,
        const unsigned* __restrict__ cursor,
        int N,
        float* __restrict__ out) {
    __shared__ float4 wnode[WIN];                     // receiver {px,py,vx,vy}
    __shared__ float4 wcoef[WIN];                     // {c0*A1, c1*A2, c2*A3, 0}
    __shared__ unsigned long long acc64[NWAVE][WIN];  // per-wave packed {x:hi,y:lo}
    int b = blockIdx.x, tid = threadIdx.x;
    int bb = b << WSH;
    int wn = min(N - bb, WIN);
    int wv = tid >> 6;

    for (int t = tid; t < wn; t += NT) {
        int g = bb + t;
        float4 r = rec16[g];
        unsigned u = __float_as_uint(r.z);
        float vx = __half2float(__ushort_as_half((unsigned short)(u & 0xFFFFu)));
        float vy = __half2float(__ushort_as_half((unsigned short)(u >> 16)));
        wnode[t] = make_float4(r.x, r.y, vx, vy);
        int ty = ptype[g];
        wcoef[t] = make_float4(p_table[3 * ty + 0] * BA1,
                               p_table[3 * ty + 1] * BA2,
                               p_table[3 * ty + 2] * BA3, 0.f);
    }
    {
        unsigned long long* a = &acc64[0][0];
        for (int t = tid; t < NWAVE * WIN; t += NT) a[t] = 0ull;
    }
    __syncthreads();

    unsigned s = (unsigned)b * CAP;
    unsigned c = cursor[b] - s;
    c = (c > CAP) ? CAP : c;
    unsigned e = s + c;

#define EDGE1(PV)                                                              \
    {                                                                          \
        unsigned p_ = (PV);                                                    \
        int l_ = (int)(p_ >> 23);                                              \
        int j_ = (int)(p_ & 0x7FFFFFu);                                        \
        float4 nj_ = rec16[j_];                                                \
        unsigned u_ = __float_as_uint(nj_.z);                                  \
        float vjx_ = __half2float(__ushort_as_half((unsigned short)(u_ & 0xFFFFu))); \
        float vjy_ = __half2float(__ushort_as_half((unsigned short)(u_ >> 16))); \
        float4 w_ = wnode[l_];                                                 \
        float4 c_ = wcoef[l_];                                                 \
        float dpx_ = nj_.x - w_.x, dpy_ = nj_.y - w_.y;                        \
        float dvx_ = vjx_ - w_.z, dvy_ = vjy_ - w_.w;                          \
        float d2_ = dpx_ * dpx_ + dpy_ * dpy_;                                 \
        float sd2_ = (d2_ > 0.f) ? d2_ : 1.f;                                  \
        float cdp_ = c_.x - c_.z / sd2_;                                       \
        float mx_ = (cdp_ * dpx_ + c_.y * dvx_) * nj_.w;                       \
        float my_ = (cdp_ * dpy_ + c_.y * dvy_) * nj_.w;                       \
        long long ax_ = (long long)(int)(mx_ * FPS);                           \
        long long ay_ = (long long)(int)(my_ * FPS);                           \
        atomicAdd(&acc64[wv][l_], (unsigned long long)((ax_ << 32) + ay_));    \
    }

    unsigned stride = (unsigned)NT * SPLIT * 4u;
    for (unsigned k0 = s + ((unsigned)blockIdx.y * NT + tid) * 4u;
         k0 + 4u <= e; k0 += stride) {
        uint4 a = *reinterpret_cast<const uint4*>(pk + k0);
        EDGE1(a.x); EDGE1(a.y); EDGE1(a.z); EDGE1(a.w);
    }
    unsigned tail = c & 3u;
    if (blockIdx.y == 0 && tid < (int)tail) EDGE1(pk[e - tail + tid]);
#undef EDGE1

    __syncthreads();
    // merge wave copies, decode fixed-point, accumulate into out
    for (int l = tid; l < wn; l += NT) {
        unsigned long long T = acc64[0][l] + acc64[1][l] +
                               acc64[2][l] + acc64[3][l];
        long long Ts = (long long)T;
        int yb = (int)(unsigned)(T & 0xFFFFFFFFull);   // signed lower sum
        long long rem = Ts - (long long)yb;            // exact multiple of 2^32
        int xb = (int)(rem >> 32);                     // signed upper sum
        atomicAdd(&out[2 * (bb + l) + 0], (float)xb * (1.f / FPS));
        atomicAdd(&out[2 * (bb + l) + 1], (float)yb * (1.f / FPS));
    }
}

// ---------------- fallback: baseline edge-parallel atomics ----------------
__global__ void boids_edge_kernel(const float* __restrict__ pos,
                                  const float* __restrict__ vel,
                                  const float* __restrict__ p_table,
                                  const float* __restrict__ field,
                                  const int* __restrict__ ptype,
                                  const int* __restrict__ dst_idx,
                                  const int* __restrict__ src_idx,
                                  float* __restrict__ out,
                                  int n_edges) {
    int e = blockIdx.x * blockDim.x + threadIdx.x;
    if (e >= n_edges) return;
    int i = dst_idx[e], j = src_idx[e];
    float2 pi = *reinterpret_cast<const float2*>(pos + 2 * i);
    float2 pj = *reinterpret_cast<const float2*>(pos + 2 * j);
    float2 vi = *reinterpret_cast<const float2*>(vel + 2 * i);
    float2 vj = *reinterpret_cast<const float2*>(vel + 2 * j);
    float dpx = pj.x - pi.x, dpy = pj.y - pi.y;
    float dvx = vj.x - vi.x, dvy = vj.y - vi.y;
    int t = ptype[i];
    float p0 = p_table[3 * t + 0], p1 = p_table[3 * t + 1], p2 = p_table[3 * t + 2];
    float d2 = dpx * dpx + dpy * dpy;
    float sd2 = (d2 > 0.0f) ? d2 : 1.0f;
    float cdp = p0 * BA1 - p2 * BA3 / sd2;
    float cdv = p1 * BA2;
    float f = field[j];
    atomicAdd(&out[2 * i + 0], (cdp * dpx + cdv * dvx) * f);
    atomicAdd(&out[2 * i + 1], (cdp * dpy + cdv * dvy) * f);
}

extern "C" void kernel_launch(void* const* d_in, const int* in_sizes, int n_in,
                              void* d_out, int out_size, void* d_ws, size_t ws_size,
                              hipStream_t stream) {
    const float* pos     = (const float*)d_in[0];   // [N,2]
    const float* vel     = (const float*)d_in[1];   // [N,2]
    const float* p_table = (const float*)d_in[2];   // [16,3]
    const float* field   = (const float*)d_in[3];   // [N,1]
    const int*   ptype   = (const int*)d_in[4];     // [N]
    const int*   eidx    = (const int*)d_in[5];     // [2,E]

    int N = in_sizes[0] / 2;
    int E = in_sizes[5] / 2;
    const int* dstI = eidx;
    const int* srcI = eidx + E;
    float* out = (float*)d_out;

    int NB    = (N + WIN - 1) >> WSH;
    int NSBLK = (E + SEPB - 1) / SEPB;
    int PBLK  = (N + NT - 1) / NT;

    // ws layout: rec16[N] float4 | pk[NB*CAP] u32 | cursor[NB] u32
    size_t off_rec = 0;
    size_t off_pk  = off_rec + (size_t)N * sizeof(float4);
    size_t off_cur = off_pk + (size_t)NB * CAP * 4;
    size_t need    = off_cur + (size_t)NB * 4;

    bool ok = (ws_size >= need) && (NB <= NBMAX) && (N <= (1 << 23)) &&
              ((E & 3) == 0) &&
              ((size_t)(E / (NB > 0 ? NB : 1)) * 3 / 2 + 64 <= CAP);

    if (!ok) {
        hipMemsetAsync(out, 0, (size_t)out_size * sizeof(float), stream);
        int grid = (E + NT - 1) / NT;
        boids_edge_kernel<<<grid, NT, 0, stream>>>(pos, vel, p_table, field,
                                                   ptype, dstI, srcI, out, E);
        return;
    }

    float4*   rec16  = (float4*)((char*)d_ws + off_rec);
    unsigned* pk     = (unsigned*)((char*)d_ws + off_pk);
    unsigned* cursor = (unsigned*)((char*)d_ws + off_cur);

    hipMemsetAsync(out, 0, (size_t)out_size * sizeof(float), stream);

    k_pack   <<<PBLK + 1, NT, 0, stream>>>(pos, vel, field, N, NB, PBLK,
                                           rec16, cursor);
    k_scatter<<<NSBLK, NTS, 0, stream>>>(dstI, srcI, E, NB, cursor, pk);
    dim3 agrid(NB, SPLIT);
    k_accum  <<<agrid, NT, 0, stream>>>(rec16, p_table, ptype, pk, cursor,
                                        N, out);
}

// Round 18
// 80.096 us; speedup vs baseline: 1.0802x; 1.0802x over previous
//
#include <hip/hip_runtime.h>
#include <hip/hip_fp16.h>

// Boids ODE segment-sum v14: v12 (79.9us proven: WIN=256, CAP-reservation,
// u64 fixed-point accum) + two scatter-local tweaks from v13:
//   1) lofs folded into gbase (gbase[b] = reserved - ex) -> 1 fewer LDS
//      read/edge in write phase.
//   2) SEPB 8192->12288 (78KB LDS, still 2 blocks/CU): runs 21->31 edges,
//      fewer blocks -> fewer reservations + scans.
// v13 lesson: WIN=512 wrecks accum (LDS 2x -> occupancy 33%); WIN stays 256.

#define BA1 5e-06f
#define BA2 0.0005f
#define BA3 1e-08f

#define NT 256        // threads per block (pack/accum)
#define NTS 1024      // threads per scatter block
#define NWAVE 4       // NT/64
#define SEPB 12288    // edges per scatter block (avg run ~31)
#define WIN 256       // receiver nodes per bucket
#define WSH 8         // log2(WIN)
#define SPLIT 8       // accum blocks per bucket
#define NBMAX 512     // max buckets
#define CAP 28672u    // per-bucket region capacity (multiple of 4)
#define FPS 4194304.f // fixed-point scale 2^22

// ---------------- K1: pack records + init cursors ----------------
// rec16[i] = {pos.x, pos.y, bitcast(f16(vel.x)|f16(vel.y)<<16), field}
__global__ void __launch_bounds__(NT)
k_pack(const float* __restrict__ pos, const float* __restrict__ vel,
       const float* __restrict__ field,
       int N, int NB, int PBLK,
       float4* __restrict__ rec16, unsigned* __restrict__ cursor) {
    int bx = blockIdx.x, tid = threadIdx.x;
    if (bx == PBLK) {
        for (int b = tid; b < NB; b += NT) cursor[b] = (unsigned)b * CAP;
        return;
    }
    int i = bx * NT + tid;
    if (i >= N) return;
    float2 p = *reinterpret_cast<const float2*>(pos + 2 * i);
    float2 v = *reinterpret_cast<const float2*>(vel + 2 * i);
    unsigned short sx = __half_as_ushort(__float2half(v.x));
    unsigned short sy = __half_as_ushort(__float2half(v.y));
    unsigned pv = (unsigned)sx | ((unsigned)sy << 16);
    rec16[i] = make_float4(p.x, p.y, __uint_as_float(pv), field[i]);
}

// ---------------- K2: multisplit scatter (1024 threads, 12 edges/thread) ----
__global__ void __launch_bounds__(NTS)
k_scatter(const int* __restrict__ dst, const int* __restrict__ src,
          int E, int NB,
          unsigned* __restrict__ cursor,
          unsigned* __restrict__ pk) {
    __shared__ unsigned lh[NBMAX];       // counts -> inclusive scan
    __shared__ unsigned lcur[NBMAX];     // running cursors (absolute sbuf slots)
    __shared__ unsigned gbase[NBMAX];    // reserved global base MINUS local ex
    __shared__ unsigned sbuf[SEPB];      // locally sorted payloads
    __shared__ unsigned short sbkt[SEPB];// bucket id per sorted slot
    int blk = blockIdx.x, tid = threadIdx.x;
    int s = blk * SEPB, e = min(E, s + SEPB);

    for (int b = tid; b < NBMAX; b += NTS) lh[b] = 0u;
    __syncthreads();

    // pass 1: local histogram
    int k = s + 4 * tid;
    for (; k + 3 < e; k += 4 * NTS) {
        int4 d = *reinterpret_cast<const int4*>(dst + k);
        atomicAdd(&lh[d.x >> WSH], 1u);
        atomicAdd(&lh[d.y >> WSH], 1u);
        atomicAdd(&lh[d.z >> WSH], 1u);
        atomicAdd(&lh[d.w >> WSH], 1u);
    }
    {
        int rem = (e - s) & 3;
        if (tid < rem) atomicAdd(&lh[dst[e - rem + tid] >> WSH], 1u);
    }
    __syncthreads();

    // inclusive Hillis-Steele scan over NBMAX, first 256 threads (2 elems each)
    // lcur snapshots the pre-scan counts first
    for (int b = tid; b < NBMAX; b += NTS) lcur[b] = lh[b];
    __syncthreads();
    for (int o = 1; o < NBMAX; o <<= 1) {
        unsigned v0 = 0u, v1 = 0u;
        if (tid < 256) {
            v0 = (tid >= o) ? lh[tid - o] : 0u;
            v1 = (tid + 256 >= o) ? lh[tid + 256 - o] : 0u;
        }
        __syncthreads();
        if (tid < 256) {
            lh[tid] += v0;
            lh[tid + 256] += v1;
        }
        __syncthreads();
    }
    // per-bucket: exclusive offset, cursor, reservation folded into gbase
    for (int b = tid; b < NBMAX; b += NTS) {
        unsigned c = lcur[b];          // saved count
        unsigned ex = lh[b] - c;       // exclusive offset
        lcur[b] = ex;
        if (b < NB && c > 0u) {
            unsigned g = atomicAdd(&cursor[b], c);
            gbase[b] = g - ex;         // write phase: idx = gbase[b] + t
        }
    }
    __syncthreads();

    // pass 2: place payloads into LDS grouped by bucket
    k = s + 4 * tid;
    for (; k + 3 < e; k += 4 * NTS) {
        int4 d = *reinterpret_cast<const int4*>(dst + k);
        int4 j = *reinterpret_cast<const int4*>(src + k);
        int b0 = d.x >> WSH; unsigned r0 = atomicAdd(&lcur[b0], 1u);
        sbuf[r0] = ((unsigned)(d.x & (WIN - 1)) << 24) | (unsigned)j.x; sbkt[r0] = (unsigned short)b0;
        int b1 = d.y >> WSH; unsigned r1 = atomicAdd(&lcur[b1], 1u);
        sbuf[r1] = ((unsigned)(d.y & (WIN - 1)) << 24) | (unsigned)j.y; sbkt[r1] = (unsigned short)b1;
        int b2 = d.z >> WSH; unsigned r2 = atomicAdd(&lcur[b2], 1u);
        sbuf[r2] = ((unsigned)(d.z & (WIN - 1)) << 24) | (unsigned)j.z; sbkt[r2] = (unsigned short)b2;
        int b3 = d.w >> WSH; unsigned r3 = atomicAdd(&lcur[b3], 1u);
        sbuf[r3] = ((unsigned)(d.w & (WIN - 1)) << 24) | (unsigned)j.w; sbkt[r3] = (unsigned short)b3;
    }
    {
        int rem = (e - s) & 3;
        if (tid < rem) {
            int kk = e - rem + tid;
            int d = dst[kk];
            int b = d >> WSH; unsigned r = atomicAdd(&lcur[b], 1u);
            sbuf[r] = ((unsigned)(d & (WIN - 1)) << 24) | (unsigned)src[kk]; sbkt[r] = (unsigned short)b;
        }
    }
    __syncthreads();

    // write phase: consecutive slots in a bucket -> consecutive global addrs
    int ne = e - s;
    for (int t = tid; t < ne; t += NTS) {
        unsigned b = sbkt[t];
        unsigned idx = gbase[b] + (unsigned)t;
        if (idx < (b + 1u) * CAP)      // safety clamp; never hit statistically
            pk[idx] = sbuf[t];
    }
}

// ---------------- K3: accumulate, ONE u64 integer LDS atomic per edge ----------
__global__ void __launch_bounds__(NT, 4)
k_accum(const float4* __restrict__ rec16,
        const float* __restrict__ p_table,
        const int* __restrict__ ptype,
        const unsigned* __restrict__ pk,
        const unsigned* __restrict__ cursor,
        int N,
        float* __restrict__ out) {
    __shared__ float4 wnode[WIN];                     // receiver {px,py,vx,vy}
    __shared__ float4 wcoef[WIN];                     // {c0*A1, c1*A2, c2*A3, 0}
    __shared__ unsigned long long acc64[NWAVE][WIN];  // per-wave packed {x:hi,y:lo}
    int b = blockIdx.x, tid = threadIdx.x;
    int bb = b << WSH;
    int wn = min(N - bb, WIN);
    int wv = tid >> 6;

    if (tid < wn) {
        int g = bb + tid;
        float4 r = rec16[g];
        unsigned u = __float_as_uint(r.z);
        float vx = __half2float(__ushort_as_half((unsigned short)(u & 0xFFFFu)));
        float vy = __half2float(__ushort_as_half((unsigned short)(u >> 16)));
        wnode[tid] = make_float4(r.x, r.y, vx, vy);
        int ty = ptype[g];
        wcoef[tid] = make_float4(p_table[3 * ty + 0] * BA1,
                                 p_table[3 * ty + 1] * BA2,
                                 p_table[3 * ty + 2] * BA3, 0.f);
    }
    {
        unsigned long long* a = &acc64[0][0];
        for (int t = tid; t < NWAVE * WIN; t += NT) a[t] = 0ull;
    }
    __syncthreads();

    unsigned s = (unsigned)b * CAP;
    unsigned c = cursor[b] - s;
    c = (c > CAP) ? CAP : c;
    unsigned e = s + c;

#define EDGE1(PV)                                                              \
    {                                                                          \
        unsigned p_ = (PV);                                                    \
        int l_ = (int)(p_ >> 24);                                              \
        int j_ = (int)(p_ & 0xFFFFFFu);                                        \
        float4 nj_ = rec16[j_];                                                \
        unsigned u_ = __float_as_uint(nj_.z);                                  \
        float vjx_ = __half2float(__ushort_as_half((unsigned short)(u_ & 0xFFFFu))); \
        float vjy_ = __half2float(__ushort_as_half((unsigned short)(u_ >> 16))); \
        float4 w_ = wnode[l_];                                                 \
        float4 c_ = wcoef[l_];                                                 \
        float dpx_ = nj_.x - w_.x, dpy_ = nj_.y - w_.y;                        \
        float dvx_ = vjx_ - w_.z, dvy_ = vjy_ - w_.w;                          \
        float d2_ = dpx_ * dpx_ + dpy_ * dpy_;                                 \
        float sd2_ = (d2_ > 0.f) ? d2_ : 1.f;                                  \
        float cdp_ = c_.x - c_.z / sd2_;                                       \
        float mx_ = (cdp_ * dpx_ + c_.y * dvx_) * nj_.w;                       \
        float my_ = (cdp_ * dpy_ + c_.y * dvy_) * nj_.w;                       \
        long long ax_ = (long long)(int)(mx_ * FPS);                           \
        long long ay_ = (long long)(int)(my_ * FPS);                           \
        atomicAdd(&acc64[wv][l_], (unsigned long long)((ax_ << 32) + ay_));    \
    }

    unsigned stride = (unsigned)NT * SPLIT * 4u;
    for (unsigned k0 = s + ((unsigned)blockIdx.y * NT + tid) * 4u;
         k0 + 4u <= e; k0 += stride) {
        uint4 a = *reinterpret_cast<const uint4*>(pk + k0);
        EDGE1(a.x); EDGE1(a.y); EDGE1(a.z); EDGE1(a.w);
    }
    unsigned tail = c & 3u;
    if (blockIdx.y == 0 && tid < (int)tail) EDGE1(pk[e - tail + tid]);
#undef EDGE1

    __syncthreads();
    // merge wave copies, decode fixed-point, accumulate into out
    for (int l = tid; l < wn; l += NT) {
        unsigned long long T = acc64[0][l] + acc64[1][l] +
                               acc64[2][l] + acc64[3][l];
        long long Ts = (long long)T;
        int yb = (int)(unsigned)(T & 0xFFFFFFFFull);   // signed lower sum
        long long rem = Ts - (long long)yb;            // exact multiple of 2^32
        int xb = (int)(rem >> 32);                     // signed upper sum
        atomicAdd(&out[2 * (bb + l) + 0], (float)xb * (1.f / FPS));
        atomicAdd(&out[2 * (bb + l) + 1], (float)yb * (1.f / FPS));
    }
}

// ---------------- fallback: baseline edge-parallel atomics ----------------
__global__ void boids_edge_kernel(const float* __restrict__ pos,
                                  const float* __restrict__ vel,
                                  const float* __restrict__ p_table,
                                  const float* __restrict__ field,
                                  const int* __restrict__ ptype,
                                  const int* __restrict__ dst_idx,
                                  const int* __restrict__ src_idx,
                                  float* __restrict__ out,
                                  int n_edges) {
    int e = blockIdx.x * blockDim.x + threadIdx.x;
    if (e >= n_edges) return;
    int i = dst_idx[e], j = src_idx[e];
    float2 pi = *reinterpret_cast<const float2*>(pos + 2 * i);
    float2 pj = *reinterpret_cast<const float2*>(pos + 2 * j);
    float2 vi = *reinterpret_cast<const float2*>(vel + 2 * i);
    float2 vj = *reinterpret_cast<const float2*>(vel + 2 * j);
    float dpx = pj.x - pi.x, dpy = pj.y - pi.y;
    float dvx = vj.x - vi.x, dvy = vj.y - vi.y;
    int t = ptype[i];
    float p0 = p_table[3 * t + 0], p1 = p_table[3 * t + 1], p2 = p_table[3 * t + 2];
    float d2 = dpx * dpx + dpy * dpy;
    float sd2 = (d2 > 0.0f) ? d2 : 1.0f;
    float cdp = p0 * BA1 - p2 * BA3 / sd2;
    float cdv = p1 * BA2;
    float f = field[j];
    atomicAdd(&out[2 * i + 0], (cdp * dpx + cdv * dvx) * f);
    atomicAdd(&out[2 * i + 1], (cdp * dpy + cdv * dvy) * f);
}

extern "C" void kernel_launch(void* const* d_in, const int* in_sizes, int n_in,
                              void* d_out, int out_size, void* d_ws, size_t ws_size,
                              hipStream_t stream) {
    const float* pos     = (const float*)d_in[0];   // [N,2]
    const float* vel     = (const float*)d_in[1];   // [N,2]
    const float* p_table = (const float*)d_in[2];   // [16,3]
    const float* field   = (const float*)d_in[3];   // [N,1]
    const int*   ptype   = (const int*)d_in[4];     // [N]
    const int*   eidx    = (const int*)d_in[5];     // [2,E]

    int N = in_sizes[0] / 2;
    int E = in_sizes[5] / 2;
    const int* dstI = eidx;
    const int* srcI = eidx + E;
    float* out = (float*)d_out;

    int NB    = (N + WIN - 1) >> WSH;
    int NSBLK = (E + SEPB - 1) / SEPB;
    int PBLK  = (N + NT - 1) / NT;

    // ws layout: rec16[N] float4 | pk[NB*CAP] u32 | cursor[NB] u32
    size_t off_rec = 0;
    size_t off_pk  = off_rec + (size_t)N * sizeof(float4);
    size_t off_cur = off_pk + (size_t)NB * CAP * 4;
    size_t need    = off_cur + (size_t)NB * 4;

    bool ok = (ws_size >= need) && (NB <= NBMAX) && (N <= (1 << 24)) &&
              ((E & 3) == 0) &&
              ((size_t)(E / (NB > 0 ? NB : 1)) * 3 / 2 + 64 <= CAP);

    if (!ok) {
        hipMemsetAsync(out, 0, (size_t)out_size * sizeof(float), stream);
        int grid = (E + NT - 1) / NT;
        boids_edge_kernel<<<grid, NT, 0, stream>>>(pos, vel, p_table, field,
                                                   ptype, dstI, srcI, out, E);
        return;
    }

    float4*   rec16  = (float4*)((char*)d_ws + off_rec);
    unsigned* pk     = (unsigned*)((char*)d_ws + off_pk);
    unsigned* cursor = (unsigned*)((char*)d_ws + off_cur);

    hipMemsetAsync(out, 0, (size_t)out_size * sizeof(float), stream);

    k_pack   <<<PBLK + 1, NT, 0, stream>>>(pos, vel, field, N, NB, PBLK,
                                           rec16, cursor);
    k_scatter<<<NSBLK, NTS, 0, stream>>>(dstI, srcI, E, NB, cursor, pk);
    dim3 agrid(NB, SPLIT);
    k_accum  <<<agrid, NT, 0, stream>>>(rec16, p_table, ptype, pk, cursor,
                                        N, out);
}

// Round 19
// 75.055 us; speedup vs baseline: 1.1527x; 1.0672x over previous
//
#include <hip/hip_runtime.h>
#include <hip/hip_fp16.h>

// Boids ODE segment-sum v15: v14 with three structural cleanups:
//   1) scatter stages dst/src in REGISTERS (24 VGPR) -> edge list read ONCE.
//   2) accum writes per-split partial slabs (non-atomic, L2-absorbed) and a
//      tiny reduce kernel sums SPLIT slabs -> out (replaces 1.6M f32 global
//      atomics that wrote through to HBM; also removes the out memset).
//   3) pack fused into the scatter kernel as extra blocks (cursors relative,
//      init by memset-0) -> one fewer dependent launch.

#define BA1 5e-06f
#define BA2 0.0005f
#define BA3 1e-08f

#define NT 256        // threads per block (accum/reduce)
#define NTS 1024      // threads per scatter block
#define NWAVE 4       // NT/64
#define SEPB 12288    // edges per scatter block (3 iters x 4 edges/thread)
#define WIN 256       // receiver nodes per bucket
#define WSH 8         // log2(WIN)
#define SPLIT 8       // accum blocks per bucket
#define NBMAX 512     // max buckets
#define CAP 28672u    // per-bucket region capacity (multiple of 4)
#define FPS 4194304.f // fixed-point scale 2^22

// ---------------- K1: fused scatter (+pack blocks) ----------------
// blocks [0, NSBLK): multisplit scatter; blocks [NSBLK, NSBLK+PB): pack rec16.
// cursor[] is RELATIVE (memset-0 before launch); global slot = b*CAP + rel.
__global__ void __launch_bounds__(NTS)
k_scatter(const int* __restrict__ dst, const int* __restrict__ src,
          const float* __restrict__ pos, const float* __restrict__ vel,
          const float* __restrict__ field,
          int E, int N, int NB, int NSBLK,
          unsigned* __restrict__ cursor,
          unsigned* __restrict__ pk,
          float4* __restrict__ rec16) {
    int bx = blockIdx.x, tid = threadIdx.x;

    if (bx >= NSBLK) {            // ---- pack role ----
        int i = (bx - NSBLK) * NTS + tid;
        if (i >= N) return;
        float2 p = *reinterpret_cast<const float2*>(pos + 2 * i);
        float2 v = *reinterpret_cast<const float2*>(vel + 2 * i);
        unsigned short sx = __half_as_ushort(__float2half(v.x));
        unsigned short sy = __half_as_ushort(__float2half(v.y));
        unsigned pv = (unsigned)sx | ((unsigned)sy << 16);
        rec16[i] = make_float4(p.x, p.y, __uint_as_float(pv), field[i]);
        return;
    }

    // ---- scatter role ----
    __shared__ unsigned lh[NBMAX];       // counts -> inclusive scan
    __shared__ unsigned lcur[NBMAX];     // count snapshot -> running cursors
    __shared__ unsigned gbase[NBMAX];    // absolute global base minus local ex
    __shared__ unsigned sbuf[SEPB];      // locally sorted payloads
    __shared__ unsigned short sbkt[SEPB];// bucket id per sorted slot
    int s = bx * SEPB, e = min(E, s + SEPB);

    for (int b = tid; b < NBMAX; b += NTS) lh[b] = 0u;
    __syncthreads();

    // single global read of this block's edges into registers (<= 12 edges)
    int k0 = s + 4 * tid;
    int k1 = k0 + 4 * NTS;
    int k2 = k0 + 8 * NTS;
    bool v0 = (k0 + 3 < e), v1 = (k1 + 3 < e), v2 = (k2 + 3 < e);
    int4 d0, d1, d2, j0, j1, j2;
    if (v0) { d0 = *reinterpret_cast<const int4*>(dst + k0);
              j0 = *reinterpret_cast<const int4*>(src + k0); }
    if (v1) { d1 = *reinterpret_cast<const int4*>(dst + k1);
              j1 = *reinterpret_cast<const int4*>(src + k1); }
    if (v2) { d2 = *reinterpret_cast<const int4*>(dst + k2);
              j2 = *reinterpret_cast<const int4*>(src + k2); }

    // pass 1: local histogram from registers
#define HIST4(D)                                                               \
    { atomicAdd(&lh[(D).x >> WSH], 1u); atomicAdd(&lh[(D).y >> WSH], 1u);      \
      atomicAdd(&lh[(D).z >> WSH], 1u); atomicAdd(&lh[(D).w >> WSH], 1u); }
    if (v0) HIST4(d0);
    if (v1) HIST4(d1);
    if (v2) HIST4(d2);
#undef HIST4
    __syncthreads();

    // snapshot counts, then inclusive Hillis-Steele scan (first 256 threads)
    for (int b = tid; b < NBMAX; b += NTS) lcur[b] = lh[b];
    __syncthreads();
    for (int o = 1; o < NBMAX; o <<= 1) {
        unsigned a0 = 0u, a1 = 0u;
        if (tid < 256) {
            a0 = (tid >= o) ? lh[tid - o] : 0u;
            a1 = (tid + 256 >= o) ? lh[tid + 256 - o] : 0u;
        }
        __syncthreads();
        if (tid < 256) {
            lh[tid] += a0;
            lh[tid + 256] += a1;
        }
        __syncthreads();
    }
    // per-bucket: exclusive offset, cursor, reservation folded into gbase
    for (int b = tid; b < NBMAX; b += NTS) {
        unsigned c = lcur[b];          // saved count
        unsigned ex = lh[b] - c;       // exclusive offset
        lcur[b] = ex;
        if (b < NB && c > 0u) {
            unsigned g = atomicAdd(&cursor[b], c);           // relative
            gbase[b] = (unsigned)b * CAP + g - ex;           // absolute base
        }
    }
    __syncthreads();

    // pass 2: place payloads into LDS grouped by bucket (from registers)
#define PLACE4(D, J)                                                           \
    {                                                                          \
        int b_ = (D).x >> WSH; unsigned r_ = atomicAdd(&lcur[b_], 1u);         \
        sbuf[r_] = ((unsigned)((D).x & (WIN - 1)) << 24) | (unsigned)(J).x;    \
        sbkt[r_] = (unsigned short)b_;                                         \
        b_ = (D).y >> WSH; r_ = atomicAdd(&lcur[b_], 1u);                      \
        sbuf[r_] = ((unsigned)((D).y & (WIN - 1)) << 24) | (unsigned)(J).y;    \
        sbkt[r_] = (unsigned short)b_;                                         \
        b_ = (D).z >> WSH; r_ = atomicAdd(&lcur[b_], 1u);                      \
        sbuf[r_] = ((unsigned)((D).z & (WIN - 1)) << 24) | (unsigned)(J).z;    \
        sbkt[r_] = (unsigned short)b_;                                         \
        b_ = (D).w >> WSH; r_ = atomicAdd(&lcur[b_], 1u);                      \
        sbuf[r_] = ((unsigned)((D).w & (WIN - 1)) << 24) | (unsigned)(J).w;    \
        sbkt[r_] = (unsigned short)b_;                                         \
    }
    if (v0) PLACE4(d0, j0);
    if (v1) PLACE4(d1, j1);
    if (v2) PLACE4(d2, j2);
#undef PLACE4
    __syncthreads();

    // write phase: consecutive slots in a bucket -> consecutive global addrs
    int ne = e - s;
    for (int t = tid; t < ne; t += NTS) {
        unsigned b = sbkt[t];
        unsigned idx = gbase[b] + (unsigned)t;
        if (idx < (b + 1u) * CAP)      // safety clamp; never hit statistically
            pk[idx] = sbuf[t];
    }
}

// ---------------- K2: accumulate -> per-split partial slabs ----------------
__global__ void __launch_bounds__(NT, 4)
k_accum(const float4* __restrict__ rec16,
        const float* __restrict__ p_table,
        const int* __restrict__ ptype,
        const unsigned* __restrict__ pk,
        const unsigned* __restrict__ cursor,
        int N, int PS,
        float* __restrict__ part) {
    __shared__ float4 wnode[WIN];                     // receiver {px,py,vx,vy}
    __shared__ float4 wcoef[WIN];                     // {c0*A1, c1*A2, c2*A3, 0}
    __shared__ unsigned long long acc64[NWAVE][WIN];  // per-wave packed {x:hi,y:lo}
    int b = blockIdx.x, tid = threadIdx.x;
    int bb = b << WSH;
    int wn = min(N - bb, WIN);
    int wv = tid >> 6;

    if (tid < wn) {
        int g = bb + tid;
        float4 r = rec16[g];
        unsigned u = __float_as_uint(r.z);
        float vx = __half2float(__ushort_as_half((unsigned short)(u & 0xFFFFu)));
        float vy = __half2float(__ushort_as_half((unsigned short)(u >> 16)));
        wnode[tid] = make_float4(r.x, r.y, vx, vy);
        int ty = ptype[g];
        wcoef[tid] = make_float4(p_table[3 * ty + 0] * BA1,
                                 p_table[3 * ty + 1] * BA2,
                                 p_table[3 * ty + 2] * BA3, 0.f);
    }
    {
        unsigned long long* a = &acc64[0][0];
        for (int t = tid; t < NWAVE * WIN; t += NT) a[t] = 0ull;
    }
    __syncthreads();

    unsigned s = (unsigned)b * CAP;
    unsigned c = cursor[b];            // relative count
    c = (c > CAP) ? CAP : c;
    unsigned e = s + c;

#define EDGE1(PV)                                                              \
    {                                                                          \
        unsigned p_ = (PV);                                                    \
        int l_ = (int)(p_ >> 24);                                              \
        int j_ = (int)(p_ & 0xFFFFFFu);                                        \
        float4 nj_ = rec16[j_];                                                \
        unsigned u_ = __float_as_uint(nj_.z);                                  \
        float vjx_ = __half2float(__ushort_as_half((unsigned short)(u_ & 0xFFFFu))); \
        float vjy_ = __half2float(__ushort_as_half((unsigned short)(u_ >> 16))); \
        float4 w_ = wnode[l_];                                                 \
        float4 c_ = wcoef[l_];                                                 \
        float dpx_ = nj_.x - w_.x, dpy_ = nj_.y - w_.y;                        \
        float dvx_ = vjx_ - w_.z, dvy_ = vjy_ - w_.w;                          \
        float d2_ = dpx_ * dpx_ + dpy_ * dpy_;                                 \
        float sd2_ = (d2_ > 0.f) ? d2_ : 1.f;                                  \
        float cdp_ = c_.x - c_.z / sd2_;                                       \
        float mx_ = (cdp_ * dpx_ + c_.y * dvx_) * nj_.w;                       \
        float my_ = (cdp_ * dpy_ + c_.y * dvy_) * nj_.w;                       \
        long long ax_ = (long long)(int)(mx_ * FPS);                           \
        long long ay_ = (long long)(int)(my_ * FPS);                           \
        atomicAdd(&acc64[wv][l_], (unsigned long long)((ax_ << 32) + ay_));    \
    }

    unsigned stride = (unsigned)NT * SPLIT * 4u;
    for (unsigned k0 = s + ((unsigned)blockIdx.y * NT + tid) * 4u;
         k0 + 4u <= e; k0 += stride) {
        uint4 a = *reinterpret_cast<const uint4*>(pk + k0);
        EDGE1(a.x); EDGE1(a.y); EDGE1(a.z); EDGE1(a.w);
    }
    unsigned tail = c & 3u;
    if (blockIdx.y == 0 && tid < (int)tail) EDGE1(pk[e - tail + tid]);
#undef EDGE1

    __syncthreads();
    // merge wave copies, decode fixed-point, write non-atomic partial slab
    float* slab = part + (size_t)blockIdx.y * PS;
    for (int l = tid; l < wn; l += NT) {
        unsigned long long T = acc64[0][l] + acc64[1][l] +
                               acc64[2][l] + acc64[3][l];
        long long Ts = (long long)T;
        int yb = (int)(unsigned)(T & 0xFFFFFFFFull);   // signed lower sum
        long long rem = Ts - (long long)yb;            // exact multiple of 2^32
        int xb = (int)(rem >> 32);                     // signed upper sum
        slab[2 * (bb + l) + 0] = (float)xb * (1.f / FPS);
        slab[2 * (bb + l) + 1] = (float)yb * (1.f / FPS);
    }
}

// ---------------- K3: reduce partial slabs -> out ----------------
__global__ void __launch_bounds__(NT)
k_reduce(const float* __restrict__ part, float* __restrict__ out,
         int total, int PS) {
    int i = blockIdx.x * NT + threadIdx.x;
    if (i >= total) return;
    float sum = 0.f;
#pragma unroll
    for (int y = 0; y < SPLIT; ++y) sum += part[(size_t)y * PS + i];
    out[i] = sum;
}

// ---------------- fallback: baseline edge-parallel atomics ----------------
__global__ void boids_edge_kernel(const float* __restrict__ pos,
                                  const float* __restrict__ vel,
                                  const float* __restrict__ p_table,
                                  const float* __restrict__ field,
                                  const int* __restrict__ ptype,
                                  const int* __restrict__ dst_idx,
                                  const int* __restrict__ src_idx,
                                  float* __restrict__ out,
                                  int n_edges) {
    int e = blockIdx.x * blockDim.x + threadIdx.x;
    if (e >= n_edges) return;
    int i = dst_idx[e], j = src_idx[e];
    float2 pi = *reinterpret_cast<const float2*>(pos + 2 * i);
    float2 pj = *reinterpret_cast<const float2*>(pos + 2 * j);
    float2 vi = *reinterpret_cast<const float2*>(vel + 2 * i);
    float2 vj = *reinterpret_cast<const float2*>(vel + 2 * j);
    float dpx = pj.x - pi.x, dpy = pj.y - pi.y;
    float dvx = vj.x - vi.x, dvy = vj.y - vi.y;
    int t = ptype[i];
    float p0 = p_table[3 * t + 0], p1 = p_table[3 * t + 1], p2 = p_table[3 * t + 2];
    float d2 = dpx * dpx + dpy * dpy;
    float sd2 = (d2 > 0.0f) ? d2 : 1.0f;
    float cdp = p0 * BA1 - p2 * BA3 / sd2;
    float cdv = p1 * BA2;
    float f = field[j];
    atomicAdd(&out[2 * i + 0], (cdp * dpx + cdv * dvx) * f);
    atomicAdd(&out[2 * i + 1], (cdp * dpy + cdv * dvy) * f);
}

extern "C" void kernel_launch(void* const* d_in, const int* in_sizes, int n_in,
                              void* d_out, int out_size, void* d_ws, size_t ws_size,
                              hipStream_t stream) {
    const float* pos     = (const float*)d_in[0];   // [N,2]
    const float* vel     = (const float*)d_in[1];   // [N,2]
    const float* p_table = (const float*)d_in[2];   // [16,3]
    const float* field   = (const float*)d_in[3];   // [N,1]
    const int*   ptype   = (const int*)d_in[4];     // [N]
    const int*   eidx    = (const int*)d_in[5];     // [2,E]

    int N = in_sizes[0] / 2;
    int E = in_sizes[5] / 2;
    const int* dstI = eidx;
    const int* srcI = eidx + E;
    float* out = (float*)d_out;

    int NB    = (N + WIN - 1) >> WSH;
    int NSBLK = (E + SEPB - 1) / SEPB;
    int PB    = (N + NTS - 1) / NTS;
    int PS    = NB * 2 * WIN;                       // partial slab stride

    // ws layout: rec16[N] float4 | pk[NB*CAP] u32 | cursor[NB] u32 | part[SPLIT*PS] f32
    size_t off_rec  = 0;
    size_t off_pk   = off_rec + (size_t)N * sizeof(float4);
    size_t off_cur  = off_pk + (size_t)NB * CAP * 4;
    size_t off_part = off_cur + (size_t)NB * 4;
    size_t need     = off_part + (size_t)SPLIT * PS * 4;

    bool ok = (ws_size >= need) && (NB <= NBMAX) && (N <= (1 << 24)) &&
              ((E & 3) == 0) && (out_size == 2 * N) &&
              ((size_t)(E / (NB > 0 ? NB : 1)) * 3 / 2 + 64 <= CAP);

    if (!ok) {
        hipMemsetAsync(out, 0, (size_t)out_size * sizeof(float), stream);
        int grid = (E + NT - 1) / NT;
        boids_edge_kernel<<<grid, NT, 0, stream>>>(pos, vel, p_table, field,
                                                   ptype, dstI, srcI, out, E);
        return;
    }

    float4*   rec16  = (float4*)((char*)d_ws + off_rec);
    unsigned* pk     = (unsigned*)((char*)d_ws + off_pk);
    unsigned* cursor = (unsigned*)((char*)d_ws + off_cur);
    float*    part   = (float*)((char*)d_ws + off_part);

    hipMemsetAsync(cursor, 0, (size_t)NB * 4, stream);

    k_scatter<<<NSBLK + PB, NTS, 0, stream>>>(dstI, srcI, pos, vel, field,
                                              E, N, NB, NSBLK,
                                              cursor, pk, rec16);
    dim3 agrid(NB, SPLIT);
    k_accum  <<<agrid, NT, 0, stream>>>(rec16, p_table, ptype, pk, cursor,
                                        N, PS, part);
    k_reduce <<<(2 * N + NT - 1) / NT, NT, 0, stream>>>(part, out, 2 * N, PS);
}